// Round 2
// baseline (561.174 us; speedup 1.0000x reference)
//
#include <hip/hip_runtime.h>

#define BB 8
#define NN 16384
#define CC 256
#define DD 32
#define EPSF 1e-6f

// ws layout (float units)
#define QBUF_FLOATS (2ull*BB*NN*DD)            // 32 MiB of normalized Q
#define ACC_STRIDE 8480                         // per (s,b): KX[32][256], xsum[256], ksum0[32]
#define ACC_OFF QBUF_FLOATS
#define ACC_FLOATS (16*ACC_STRIDE)
#define FIN_OFF (ACC_OFF + ACC_FLOATS)
#define FIN_STRIDE 8480
#define WBF_OFF (FIN_OFF + 16*FIN_STRIDE)       // 32768 ushort = 16384 floats

typedef __attribute__((ext_vector_type(8))) short bh8;
typedef __attribute__((ext_vector_type(4))) float f4;

__device__ __forceinline__ unsigned int bfp(float f) {
    unsigned int u = __float_as_uint(f);
    return (u + 0x7FFFu + ((u >> 16) & 1u)) >> 16;   // RNE fp32->bf16 bits
}

// ---------------------------------------------------------------------------
// k0: convert the 4 projection weight matrices to bf16 once.
// wbf layout: [Wk, Wq, Wky, Wqy], each 32x256.
// ---------------------------------------------------------------------------
__global__ __launch_bounds__(256)
void k0_cvt(const float* __restrict__ Wk, const float* __restrict__ Wq,
            const float* __restrict__ Wky, const float* __restrict__ Wqy,
            unsigned short* __restrict__ wbf)
{
    int i = blockIdx.x * 256 + threadIdx.x;      // 0..32767
    const float* p = (i < 8192) ? Wk : (i < 16384) ? Wq : (i < 24576) ? Wky : Wqy;
    wbf[i] = (unsigned short)bfp(p[i & 8191]);
}

// ---------------------------------------------------------------------------
// k1: per (64-pos-group x4 chunks, batch, stream):
//   GEMM1 (MFMA): D[p][d] = X.W^T + bias  (d 0..31 = K rows, 32..63 = Q rows)
//   norms via shfl within the wave's 16-position strip
//   normalized Q -> qbuf (fp32); normalized K -> LDS bf16 [d][p]
//   GEMM2 (MFMA): KX[d][c] += K.X  (X re-read from global, L2-hot)
//   ksum/xsum in fp32 registers -> atomics.
// ---------------------------------------------------------------------------
__global__ __launch_bounds__(256, 4)
void k1_proj(const float* __restrict__ x, const float* __restrict__ y,
             const unsigned short* __restrict__ wbf,
             const float* __restrict__ bk, const float* __restrict__ bq,
             const float* __restrict__ bky, const float* __restrict__ bqy,
             float* __restrict__ qbuf, float* __restrict__ acc)
{
    const int b = blockIdx.y, s = blockIdx.z;
    const float* __restrict__ src = (s ? y : x) + (size_t)b * NN * CC;
    const unsigned short* __restrict__ wk = wbf + (s ? 2 : 0) * 8192;
    const unsigned short* __restrict__ wq = wbf + (s ? 3 : 1) * 8192;
    const float* __restrict__ bkp = s ? bky : bk;
    const float* __restrict__ bqp = s ? bqy : bq;
    float* __restrict__ qb = qbuf + (size_t)(s*BB + b) * NN * DD;
    float* __restrict__ accsb = acc + (size_t)(s*BB + b) * ACC_STRIDE;

    __shared__ unsigned short Xs[64][272];   // bf16 X chunk, 34,816 B
    __shared__ unsigned short Ksb[32][72];   // bf16 normalized K [d][p], 4,608 B
    __shared__ float red[4][32];             // ksum cross-wave, 512 B

    const int tid = threadIdx.x;
    const int w = tid >> 6;                  // wave 0..3 (owns p-strip 16w..16w+15)
    const int lane = tid & 63;
    const int l15 = lane & 15, l4 = lane >> 4;
    const int c0 = 4 * lane;                 // staging channel quad

    const float biasv[4] = { bkp[l15], bkp[16 + l15], bqp[l15], bqp[16 + l15] };

    f4 g2acc[2][4];
    #pragma unroll
    for (int dt = 0; dt < 2; ++dt)
        #pragma unroll
        for (int ct = 0; ct < 4; ++ct) g2acc[dt][ct] = (f4){0.f, 0.f, 0.f, 0.f};
    float kacc0 = 0.f, kacc1 = 0.f;
    float xs0 = 0.f, xs1 = 0.f, xs2 = 0.f, xs3 = 0.f;

    for (int ch = 0; ch < 4; ++ch) {
        const int p0 = (blockIdx.x * 4 + ch) * 64;

        // ---- stage X chunk -> bf16 LDS (+ fp32 xsum partials)
        for (int m = 0; m < 4; ++m) {
            #pragma unroll
            for (int i = 0; i < 4; ++i) {
                int row = 16 * m + 4 * w + i;
                float4 v = *(const float4*)(src + (size_t)(p0 + row) * CC + c0);
                xs0 += v.x; xs1 += v.y; xs2 += v.z; xs3 += v.w;
                unsigned int lo = bfp(v.x) | (bfp(v.y) << 16);
                unsigned int hi = bfp(v.z) | (bfp(v.w) << 16);
                *(uint2*)&Xs[row][c0] = make_uint2(lo, hi);
            }
        }
        __syncthreads();

        // ---- GEMM1: D[p][d] tiles; acc init = bias (bias is per-col d)
        f4 a1[4];
        #pragma unroll
        for (int dt = 0; dt < 4; ++dt)
            a1[dt] = (f4){biasv[dt], biasv[dt], biasv[dt], biasv[dt]};
        #pragma unroll
        for (int ks = 0; ks < 8; ++ks) {
            bh8 xa = *(const bh8*)&Xs[16 * w + l15][32 * ks + 8 * l4];
            bh8 w0 = *(const bh8*)(wk + (size_t)(l15) * 256 + 32 * ks + 8 * l4);
            bh8 w1 = *(const bh8*)(wk + (size_t)(16 + l15) * 256 + 32 * ks + 8 * l4);
            bh8 w2 = *(const bh8*)(wq + (size_t)(l15) * 256 + 32 * ks + 8 * l4);
            bh8 w3 = *(const bh8*)(wq + (size_t)(16 + l15) * 256 + 32 * ks + 8 * l4);
            a1[0] = __builtin_amdgcn_mfma_f32_16x16x32_bf16(xa, w0, a1[0], 0, 0, 0);
            a1[1] = __builtin_amdgcn_mfma_f32_16x16x32_bf16(xa, w1, a1[1], 0, 0, 0);
            a1[2] = __builtin_amdgcn_mfma_f32_16x16x32_bf16(xa, w2, a1[2], 0, 0, 0);
            a1[3] = __builtin_amdgcn_mfma_f32_16x16x32_bf16(xa, w3, a1[3], 0, 0, 0);
        }

        // ---- norms: per-lane partials over d={l15,16+l15}, shfl over l15
        float ssK[4], ssQ[4];
        #pragma unroll
        for (int r = 0; r < 4; ++r) {
            ssK[r] = a1[0][r] * a1[0][r] + a1[1][r] * a1[1][r];
            ssQ[r] = a1[2][r] * a1[2][r] + a1[3][r] * a1[3][r];
        }
        #pragma unroll
        for (int off = 1; off < 16; off <<= 1) {
            #pragma unroll
            for (int r = 0; r < 4; ++r) {
                ssK[r] += __shfl_xor(ssK[r], off);
                ssQ[r] += __shfl_xor(ssQ[r], off);
            }
        }
        float nK[4], nQ[4];
        #pragma unroll
        for (int r = 0; r < 4; ++r) { nK[r] = rsqrtf(ssK[r]); nQ[r] = rsqrtf(ssQ[r]); }

        // ---- normalized K -> LDS bf16 [d][p] (4 consecutive p per store)
        #pragma unroll
        for (int dt = 0; dt < 2; ++dt) {
            unsigned int lo = bfp(a1[dt][0] * nK[0]) | (bfp(a1[dt][1] * nK[1]) << 16);
            unsigned int hi = bfp(a1[dt][2] * nK[2]) | (bfp(a1[dt][3] * nK[3]) << 16);
            *(uint2*)&Ksb[16 * dt + l15][16 * w + 4 * l4] = make_uint2(lo, hi);
        }
        // ---- ksum partials (fp32)
        kacc0 += a1[0][0]*nK[0] + a1[0][1]*nK[1] + a1[0][2]*nK[2] + a1[0][3]*nK[3];
        kacc1 += a1[1][0]*nK[0] + a1[1][1]*nK[1] + a1[1][2]*nK[2] + a1[1][3]*nK[3];
        // ---- normalized Q -> global (fp32)
        #pragma unroll
        for (int dt = 2; dt < 4; ++dt)
            #pragma unroll
            for (int r = 0; r < 4; ++r)
                qb[(size_t)(p0 + 16 * w + 4 * l4 + r) * DD + 16 * (dt - 2) + l15] =
                    a1[dt][r] * nQ[r];
        __syncthreads();

        // ---- GEMM2: KX[d][c] += K[d][p] * X[p][c], X from global (L2-hot)
        #pragma unroll
        for (int ks2 = 0; ks2 < 2; ++ks2) {
            bh8 af0 = *(const bh8*)&Ksb[l15][32 * ks2 + 8 * l4];
            bh8 af1 = *(const bh8*)&Ksb[16 + l15][32 * ks2 + 8 * l4];
            #pragma unroll
            for (int ct = 0; ct < 4; ++ct) {
                int cc = 64 * w + 16 * ct + l15;
                const float* xp = src + (size_t)(p0 + 32 * ks2 + 8 * l4) * CC + cc;
                unsigned int q0 = bfp(xp[0])        | (bfp(xp[256])  << 16);
                unsigned int q1 = bfp(xp[512])      | (bfp(xp[768])  << 16);
                unsigned int q2 = bfp(xp[1024])     | (bfp(xp[1280]) << 16);
                unsigned int q3 = bfp(xp[1536])     | (bfp(xp[1792]) << 16);
                union { unsigned int u[4]; bh8 v; } bfr;
                bfr.u[0] = q0; bfr.u[1] = q1; bfr.u[2] = q2; bfr.u[3] = q3;
                g2acc[0][ct] = __builtin_amdgcn_mfma_f32_16x16x32_bf16(af0, bfr.v, g2acc[0][ct], 0, 0, 0);
                g2acc[1][ct] = __builtin_amdgcn_mfma_f32_16x16x32_bf16(af1, bfr.v, g2acc[1][ct], 0, 0, 0);
            }
        }
    }

    // ---- epilogue: reductions + atomics
    kacc0 += __shfl_xor(kacc0, 16); kacc0 += __shfl_xor(kacc0, 32);
    kacc1 += __shfl_xor(kacc1, 16); kacc1 += __shfl_xor(kacc1, 32);
    if (lane < 16) { red[w][l15] = kacc0; red[w][16 + l15] = kacc1; }
    atomicAdd(accsb + 8192 + c0 + 0, xs0);
    atomicAdd(accsb + 8192 + c0 + 1, xs1);
    atomicAdd(accsb + 8192 + c0 + 2, xs2);
    atomicAdd(accsb + 8192 + c0 + 3, xs3);
    __syncthreads();
    if (tid < 32)
        atomicAdd(accsb + 8448 + tid, red[0][tid] + red[1][tid] + red[2][tid] + red[3][tid]);
    #pragma unroll
    for (int dt = 0; dt < 2; ++dt)
        #pragma unroll
        for (int ct = 0; ct < 4; ++ct)
            #pragma unroll
            for (int r = 0; r < 4; ++r)
                atomicAdd(accsb + (size_t)(16 * dt + 4 * l4 + r) * 256 + 64 * w + 16 * ct + l15,
                          g2acc[dt][ct][r]);
}

// ---------------------------------------------------------------------------
// Kernel 2: finalize per (b,s): mat = KX @ Wv^T + ksum0 (x) bv ; vsum = Wv@xsum + N*bv
// ---------------------------------------------------------------------------
__global__ __launch_bounds__(256, 2)
void k2_finalize(const float* __restrict__ Wv, const float* __restrict__ bv,
                 const float* __restrict__ Wvy, const float* __restrict__ bvy,
                 const float* __restrict__ acc, float* __restrict__ fin)
{
    const int b = blockIdx.x, s = blockIdx.y;
    const float* __restrict__ Wv_ = s ? Wvy : Wv;
    const float* __restrict__ bv_ = s ? bvy : bv;
    const float* __restrict__ a = acc + (size_t)(s*BB + b) * ACC_STRIDE;
    float* __restrict__ f = fin + (size_t)(s*BB + b) * FIN_STRIDE;

    __shared__ float KXt[256][36];   // transposed KX: [c'][d]
    __shared__ float xs[256];
    __shared__ float ks0[32];

    const int tid = threadIdx.x;
    for (int d = 0; d < 32; ++d) KXt[tid][d] = a[d*256 + tid];
    xs[tid] = a[8192 + tid];
    if (tid < 32) { float v = a[8448 + tid]; ks0[tid] = v; f[8448 + tid] = v + EPSF; }
    __syncthreads();

    const int dh = tid >> 7;                 // d-range dh*16..+15
    const int c0 = (tid & 127) * 2;
    float macc[16][2];
    #pragma unroll
    for (int i = 0; i < 16; ++i) { macc[i][0]=0.f; macc[i][1]=0.f; }
    float v0 = 0.f, v1 = 0.f;

    for (int k4 = 0; k4 < 256; k4 += 4) {
        float4 wa = *(const float4*)(Wv_ + (size_t)c0*256 + k4);
        float4 wb = *(const float4*)(Wv_ + (size_t)(c0+1)*256 + k4);
        float4 xv = *(const float4*)&xs[k4];
        v0 += wa.x*xv.x + wa.y*xv.y + wa.z*xv.z + wa.w*xv.w;
        v1 += wb.x*xv.x + wb.y*xv.y + wb.z*xv.z + wb.w*xv.w;
        #pragma unroll
        for (int u = 0; u < 4; ++u) {
            float wau = (u==0)?wa.x:(u==1)?wa.y:(u==2)?wa.z:wa.w;
            float wbu = (u==0)?wb.x:(u==1)?wb.y:(u==2)?wb.z:wb.w;
            #pragma unroll
            for (int i4 = 0; i4 < 16; i4 += 4) {
                float4 kxv = *(const float4*)&KXt[k4+u][dh*16 + i4];
                macc[i4+0][0] += kxv.x*wau; macc[i4+0][1] += kxv.x*wbu;
                macc[i4+1][0] += kxv.y*wau; macc[i4+1][1] += kxv.y*wbu;
                macc[i4+2][0] += kxv.z*wau; macc[i4+2][1] += kxv.z*wbu;
                macc[i4+3][0] += kxv.w*wau; macc[i4+3][1] += kxv.w*wbu;
            }
        }
    }
    float bvc0 = bv_[c0], bvc1 = bv_[c0+1];
    if (dh == 0) {
        f[8192 + c0]     = v0 + (float)NN * bvc0;
        f[8192 + c0 + 1] = v1 + (float)NN * bvc1;
    }
    #pragma unroll
    for (int i = 0; i < 16; ++i) {
        int d = dh*16 + i;
        f[d*256 + c0]     = macc[i][0] + ks0[d]*bvc0;
        f[d*256 + c0 + 1] = macc[i][1] + ks0[d]*bvc1;
    }
}

// ---------------------------------------------------------------------------
// Kernel 3: outputs. Per block: batch b, 64 positions, BOTH streams.
//   F[r][c] = sv[r]*vsum_s[c] + sum_k At[k][r]*Ms[k][c],  Ms = [mat; maty]
// ---------------------------------------------------------------------------
__global__ __launch_bounds__(512, 2)
void k3_output(const float* __restrict__ qbuf, const float* __restrict__ fin,
               const float* __restrict__ g_gamma, const float* __restrict__ g_gammay,
               const float* __restrict__ g_gammacx, const float* __restrict__ g_gammacy,
               const float* __restrict__ g_wx1, const float* __restrict__ g_wx2,
               const float* __restrict__ g_wy1, const float* __restrict__ g_wy2,
               float* __restrict__ out)
{
    const int b = blockIdx.y;
    const int p0 = blockIdx.x * 64;
    const float* __restrict__ fx_ = fin + (size_t)(0*BB + b) * FIN_STRIDE;
    const float* __restrict__ fy_ = fin + (size_t)(1*BB + b) * FIN_STRIDE;

    __shared__ float Ms[64][260];
    __shared__ float At[64][132];
    __shared__ float vs[2][256];
    __shared__ float ksl[2][32];
    __shared__ float sv[128];

    const int tid = threadIdx.x;
    if (tid < 256) { vs[0][tid] = fx_[8192 + tid]; vs[1][tid] = fy_[8192 + tid]; }
    else if (tid < 320) { int t = tid - 256; ksl[t >> 5][t & 31] = ((t < 32) ? fx_ : fy_)[8448 + (t & 31)]; }
    __syncthreads();

    if (tid < 128) {
        const int str = tid >> 6;
        const int p = p0 + (tid & 63);
        const float* __restrict__ qp = qbuf + ((size_t)(str*BB + b) * NN + p) * DD;
        float q[32];
        float ss = 0.f;
        #pragma unroll
        for (int m = 0; m < 8; ++m) {
            float4 v = *(const float4*)(qp + m*4);
            q[m*4+0]=v.x; q[m*4+1]=v.y; q[m*4+2]=v.z; q[m*4+3]=v.w;
            ss += v.x*v.x + v.y*v.y + v.z*v.z + v.w*v.w;
        }
        float qn = rsqrtf(ss);
        float dK = 0.f, dKy = 0.f;
        #pragma unroll
        for (int d = 0; d < 32; ++d) { dK += q[d]*ksl[0][d]; dKy += q[d]*ksl[1][d]; }
        dK *= qn; dKy *= qn;
        float clo, chi, svr;
        if (str == 0) {
            float t1 = 1.f / ((float)NN + dK);
            float t2 = 1.f / ((float)NN + dKy);
            float a1 = g_gamma[0]   * g_wx1[0] * t1;
            float a2 = g_gammacx[0] * g_wx2[0] * t2;
            clo = a1 * qn; chi = a2 * qn; svr = a1 + a2;
        } else {
            float ty1 = 1.f / ((float)NN + dKy);
            float ty2 = 1.f / ((float)NN + dK);
            float b1 = g_gammay[0]  * g_wy1[0] * ty1;
            float b2 = g_gammacy[0] * g_wy2[0] * ty2;
            clo = b2 * qn; chi = b1 * qn; svr = b1 + b2;
        }
        sv[tid] = svr;
        #pragma unroll
        for (int k = 0; k < 32; ++k) At[k][tid]      = clo * q[k];
        #pragma unroll
        for (int k = 0; k < 32; ++k) At[32 + k][tid] = chi * q[k];
    } else {
        for (int f4i = tid - 128; f4i < 4096; f4i += 384) {
            int flat = f4i * 4;
            int k = flat >> 8, c = flat & 255;
            const float* __restrict__ srcp = (k < 32) ? (fx_ + k*256 + c) : (fy_ + (k-32)*256 + c);
            *(float4*)&Ms[k][c] = *(const float4*)srcp;
        }
    }
    __syncthreads();

    const int rg = tid >> 5, cg = tid & 31;
    const int r0 = rg * 8;
    const int cA = cg * 4, cB2 = 128 + cg * 4;
    float accr[8][8];
    #pragma unroll
    for (int i = 0; i < 8; ++i)
        #pragma unroll
        for (int m = 0; m < 8; ++m) accr[i][m] = 0.f;

    #pragma unroll 2
    for (int k = 0; k < 64; ++k) {
        float4 a0 = *(const float4*)&At[k][r0];
        float4 a1 = *(const float4*)&At[k][r0 + 4];
        float4 m0 = *(const float4*)&Ms[k][cA];
        float4 m1 = *(const float4*)&Ms[k][cB2];
        float av[8] = {a0.x, a0.y, a0.z, a0.w, a1.x, a1.y, a1.z, a1.w};
        #pragma unroll
        for (int i = 0; i < 8; ++i) {
            accr[i][0] += av[i]*m0.x; accr[i][1] += av[i]*m0.y;
            accr[i][2] += av[i]*m0.z; accr[i][3] += av[i]*m0.w;
            accr[i][4] += av[i]*m1.x; accr[i][5] += av[i]*m1.y;
            accr[i][6] += av[i]*m1.z; accr[i][7] += av[i]*m1.w;
        }
    }

    float* __restrict__ fxout = out;
    float* __restrict__ fyout = out + (size_t)BB * NN * CC;
    const int str = rg >> 3;
    const float* __restrict__ vrow = vs[str];
    float4 vA = *(const float4*)&vrow[cA];
    float4 vB = *(const float4*)&vrow[cB2];
    #pragma unroll
    for (int i = 0; i < 8; ++i) {
        int r = r0 + i;
        int p = p0 + (r & 63);
        float svr = sv[r];
        float4 o0 = make_float4(accr[i][0] + svr*vA.x, accr[i][1] + svr*vA.y,
                                accr[i][2] + svr*vA.z, accr[i][3] + svr*vA.w);
        float4 o1 = make_float4(accr[i][4] + svr*vB.x, accr[i][5] + svr*vB.y,
                                accr[i][6] + svr*vB.z, accr[i][7] + svr*vB.w);
        float* __restrict__ op = (str ? fyout : fxout) + ((size_t)b * NN + p) * CC;
        *(float4*)(op + cA)  = o0;
        *(float4*)(op + cB2) = o1;
    }
}

extern "C" void kernel_launch(void* const* d_in, const int* in_sizes, int n_in,
                              void* d_out, int out_size, void* d_ws, size_t ws_size,
                              hipStream_t stream)
{
    (void)in_sizes; (void)n_in; (void)out_size; (void)ws_size;
    const float* x   = (const float*)d_in[0];
    const float* y   = (const float*)d_in[1];
    const float* Wq  = (const float*)d_in[2];
    const float* bq  = (const float*)d_in[3];
    const float* Wk  = (const float*)d_in[4];
    const float* bk  = (const float*)d_in[5];
    const float* Wv  = (const float*)d_in[6];
    const float* bv  = (const float*)d_in[7];
    const float* Wqy = (const float*)d_in[8];
    const float* bqy = (const float*)d_in[9];
    const float* Wky = (const float*)d_in[10];
    const float* bky = (const float*)d_in[11];
    const float* Wvy = (const float*)d_in[12];
    const float* bvy = (const float*)d_in[13];

    float* ws   = (float*)d_ws;
    float* qbuf = ws;
    float* acc  = ws + ACC_OFF;
    float* fin  = ws + FIN_OFF;
    unsigned short* wbf = (unsigned short*)(ws + WBF_OFF);

    k0_cvt<<<128, 256, 0, stream>>>(Wk, Wq, Wky, Wqy, wbf);
    hipMemsetAsync(acc, 0, ACC_FLOATS * sizeof(float), stream);

    k1_proj<<<dim3(64, BB, 2), 256, 0, stream>>>(x, y, wbf, bk, bq, bky, bqy, qbuf, acc);
    k2_finalize<<<dim3(BB, 2), 256, 0, stream>>>(Wv, bv, Wvy, bvy, acc, fin);
    k3_output<<<dim3(NN/64, BB), 512, 0, stream>>>(qbuf, fin,
        (const float*)d_in[14], (const float*)d_in[15], (const float*)d_in[16], (const float*)d_in[17],
        (const float*)d_in[18], (const float*)d_in[19], (const float*)d_in[20], (const float*)d_in[21],
        (float*)d_out);
}